// Round 1
// baseline (1470.863 us; speedup 1.0000x reference)
//
#include <hip/hip_runtime.h>

#define HW_PIX 12544          // 112*112
#define M_TOTAL 802816        // 64*112*112 (pixels per channel)
#define CHUNKS_PER_B 49       // 12544 / 256
#define GRID1 784             // 3136 chunks / 4 per block
#define EPS_IN 1e-5f

typedef __attribute__((ext_vector_type(8))) short bf16x8_t;   // 8 bf16 = 4 VGPR
typedef __attribute__((ext_vector_type(4))) float f32x4_t;

__device__ __forceinline__ unsigned short f2bf(float f) {
  union { float f; unsigned u; } v; v.f = f;
  unsigned r = v.u + 0x7FFFu + ((v.u >> 16) & 1u);   // round-to-nearest-even
  return (unsigned short)(r >> 16);
}

// ---------------- Pass 1: per-channel sums + raw gram G = X X^T (bf16 MFMA) ----
// ws layout: G fp32 [4096] | sums [64] | wm [4096] | bias [64] | sigma_n [4096]
__global__ __launch_bounds__(256) void k_gram(const float* __restrict__ x,
                                              float* __restrict__ G,
                                              float* __restrict__ sums) {
  // 64 channels x 256 pixels bf16, +8 pad (row = 528 B -> frag reads 2-way-free)
  __shared__ unsigned short xs[64][264];
  const int t    = threadIdx.x;
  const int lane = t & 63;
  const int wv   = t >> 6;       // wave id 0..3 -> owns gram row-block wv
  const int c    = t >> 2;       // staging channel
  const int qb   = t & 3;        // staging quad offset
  f32x4_t acc[4];
  #pragma unroll
  for (int i = 0; i < 4; ++i) acc[i] = (f32x4_t){0.f, 0.f, 0.f, 0.f};
  float sloc = 0.f;

  for (int itc = 0; itc < 4; ++itc) {
    const int ci = blockIdx.x + itc * GRID1;            // chunk id [0,3136)
    const int b  = ci / CHUNKS_PER_B;
    const int p0 = (ci - b * CHUNKS_PER_B) * 256;
    const float4* src4 = (const float4*)(x + ((size_t)(b * 64 + c)) * HW_PIX + p0);
    #pragma unroll
    for (int i2 = 0; i2 < 16; ++i2) {
      const int q = qb + 4 * i2;
      float4 v = src4[q];
      sloc += (v.x + v.y) + (v.z + v.w);
      ushort4 h;
      h.x = f2bf(v.x); h.y = f2bf(v.y); h.z = f2bf(v.z); h.w = f2bf(v.w);
      *(ushort4*)&xs[c][4 * q] = h;
    }
    __syncthreads();
    // A-frag == B-frag load pattern (gram trick): layout-robust by construction.
    #pragma unroll
    for (int ks = 0; ks < 8; ++ks) {
      const int col = ks * 32 + 8 * (lane >> 4);
      bf16x8_t fa = *(const bf16x8_t*)&xs[wv * 16 + (lane & 15)][col];
      #pragma unroll
      for (int cb = 0; cb < 4; ++cb) {
        bf16x8_t fb = *(const bf16x8_t*)&xs[cb * 16 + (lane & 15)][col];
        acc[cb] = __builtin_amdgcn_mfma_f32_16x16x32_bf16(fa, fb, acc[cb], 0, 0, 0);
      }
    }
    __syncthreads();
  }
  atomicAdd(&sums[c], sloc);
  // C/D map (m89-verified): col = lane&15, row = (lane>>4)*4 + reg
  const int g = lane >> 4, cl = lane & 15;
  #pragma unroll
  for (int cb = 0; cb < 4; ++cb)
    #pragma unroll
    for (int rg = 0; rg < 4; ++rg)
      atomicAdd(&G[(wv * 16 + g * 4 + rg) * 64 + cb * 16 + cl], acc[cb][rg]);
}

// ---------------- Pass 2: Newton-Schulz on 64x64, single block -----------------
// All iterates are symmetric (polynomials of sigma_n) -> B[k][j] = B[j][k],
// so every matmul is dot(Xrow_i, Yrow_j): row-major float4 reads only.
__device__ __forceinline__ void mm_core(float acc[4][4], const float (*X)[68],
                                        const float (*Y)[68], int iB, int jB) {
  #pragma unroll
  for (int a = 0; a < 4; ++a)
    #pragma unroll
    for (int b = 0; b < 4; ++b) acc[a][b] = 0.f;
  #pragma unroll 4
  for (int kq = 0; kq < 16; ++kq) {
    float4 xr[4], yr[4];
    #pragma unroll
    for (int d = 0; d < 4; ++d) {
      xr[d] = *(const float4*)&X[iB + 16 * d][4 * kq];  // uniform per 16 lanes
      yr[d] = *(const float4*)&Y[jB + 16 * d][4 * kq];  // lane-consecutive rows
    }
    #pragma unroll
    for (int di = 0; di < 4; ++di)
      #pragma unroll
      for (int dj = 0; dj < 4; ++dj)
        acc[di][dj] += xr[di].x * yr[dj].x + xr[di].y * yr[dj].y +
                       xr[di].z * yr[dj].z + xr[di].w * yr[dj].w;
  }
}

__global__ __launch_bounds__(256) void k_ns(float* __restrict__ ws) {
  float* G    = ws;
  float* sums = ws + 4096;
  float* wm   = ws + 4160;
  float* bias = ws + 8256;
  float* Sg   = ws + 8320;   // sigma_n kept in global (L1/L2-hot), saves LDS
  __shared__ float bufs[3][64][68];
  __shared__ float mean_s[64];
  __shared__ float r_s;
  const int t = threadIdx.x;
  const float inv_m = 1.0f / (float)M_TOTAL;
  if (t < 64) mean_s[t] = sums[t] * inv_m;
  __syncthreads();
  for (int idx = t; idx < 4096; idx += 256) {
    int i = idx >> 6, j = idx & 63;
    bufs[1][i][j] = G[idx] * inv_m - mean_s[i] * mean_s[j] + ((i == j) ? EPS_IN : 0.f);
  }
  __syncthreads();
  if (t == 0) {
    float tr = 0.f;
    for (int i = 0; i < 64; ++i) tr += bufs[1][i][i];
    r_s = 1.0f / tr;
  }
  __syncthreads();
  const float r = r_s;
  for (int idx = t; idx < 4096; idx += 256) {
    int i = idx >> 6, j = idx & 63;
    Sg[idx] = bufs[1][i][j] * r;
    bufs[0][i][j] = (i == j) ? 1.f : 0.f;   // P = I
  }
  __syncthreads();
  int pa = 0, pb = 1, pc = 2;
  const int iB = t >> 4, jB = t & 15;       // strided 4x4 output blocks
  float acc[4][4];
  for (int itn = 0; itn < 5; ++itn) {
    // B = P*P
    mm_core(acc, (const float(*)[68])bufs[pa], (const float(*)[68])bufs[pa], iB, jB);
    #pragma unroll
    for (int di = 0; di < 4; ++di)
      #pragma unroll
      for (int dj = 0; dj < 4; ++dj)
        bufs[pb][iB + 16 * di][jB + 16 * dj] = acc[di][dj];
    __syncthreads();
    // C = B*P
    mm_core(acc, (const float(*)[68])bufs[pb], (const float(*)[68])bufs[pa], iB, jB);
    #pragma unroll
    for (int di = 0; di < 4; ++di)
      #pragma unroll
      for (int dj = 0; dj < 4; ++dj)
        bufs[pc][iB + 16 * di][jB + 16 * dj] = acc[di][dj];
    __syncthreads();
    // reload sigma_n into B slot (B is dead now)
    for (int idx = t; idx < 4096; idx += 256)
      bufs[pb][idx >> 6][idx & 63] = Sg[idx];
    __syncthreads();
    // P' = 1.5 P - 0.5 * C*S   (into C's slot after all reads complete)
    mm_core(acc, (const float(*)[68])bufs[pc], (const float(*)[68])bufs[pb], iB, jB);
    __syncthreads();
    #pragma unroll
    for (int di = 0; di < 4; ++di)
      #pragma unroll
      for (int dj = 0; dj < 4; ++dj) {
        int ii = iB + 16 * di, jj = jB + 16 * dj;
        bufs[pc][ii][jj] = 1.5f * bufs[pa][ii][jj] - 0.5f * acc[di][dj];
      }
    __syncthreads();
    int tmp = pa; pa = pc; pc = tmp;
  }
  const float sr = sqrtf(r);
  for (int idx = t; idx < 4096; idx += 256)
    wm[idx] = bufs[pa][idx >> 6][idx & 63] * sr;
  if (t < 64) {
    float a = 0.f;
    for (int k = 0; k < 64; ++k) a += bufs[pa][t][k] * mean_s[k];
    bias[t] = -a * sr;
  }
}

// ---------------- Pass 3: out = wm * x + bias (fp32, memory-bound) -------------
__global__ __launch_bounds__(256) void k_apply(const float* __restrict__ x,
                                               const float* __restrict__ wmb,
                                               float* __restrict__ out) {
  const int i = blockIdx.x * 256 + threadIdx.x;   // pixel id [0, 802816)
  const int b = i / HW_PIX;
  const int p = i - b * HW_PIX;
  const float* __restrict__ wm   = wmb;           // 64x64, wave-uniform -> s_load
  const float* __restrict__ bias = wmb + 4096;
  const float* xb = x + (size_t)b * 64 * HW_PIX + p;
  float xk[64];
  #pragma unroll
  for (int k = 0; k < 64; ++k) xk[k] = xb[(size_t)k * HW_PIX];
  float* ob = out + (size_t)b * 64 * HW_PIX + p;
  #pragma unroll 1
  for (int c = 0; c < 64; ++c) {
    const float4* wr = (const float4*)(wm + c * 64);
    float a0 = bias[c], a1 = 0.f, a2 = 0.f, a3 = 0.f;  // 4 chains for ILP
    #pragma unroll
    for (int k4 = 0; k4 < 16; ++k4) {
      float4 w = wr[k4];
      a0 += w.x * xk[4 * k4 + 0];
      a1 += w.y * xk[4 * k4 + 1];
      a2 += w.z * xk[4 * k4 + 2];
      a3 += w.w * xk[4 * k4 + 3];
    }
    ob[(size_t)c * HW_PIX] = (a0 + a1) + (a2 + a3);
  }
}

extern "C" void kernel_launch(void* const* d_in, const int* in_sizes, int n_in,
                              void* d_out, int out_size, void* d_ws, size_t ws_size,
                              hipStream_t stream) {
  const float* x = (const float*)d_in[0];
  float* out = (float*)d_out;
  float* ws  = (float*)d_ws;
  // zero G + sums (ws is poisoned 0xAA before every launch)
  hipMemsetAsync(d_ws, 0, 4160 * sizeof(float), stream);
  k_gram<<<GRID1, 256, 0, stream>>>(x, ws, ws + 4096);
  k_ns<<<1, 256, 0, stream>>>(ws);
  k_apply<<<3136, 256, 0, stream>>>(x, ws + 4160, out);
}

// Round 2
// 600.814 us; speedup vs baseline: 2.4481x; 2.4481x over previous
//
#include <hip/hip_runtime.h>

#define HW_PIX 12544          // 112*112
#define M_TOTAL 802816        // 64*112*112
#define TILES_PER_B 49        // 12544 / 256
#define NBLK 3136             // 64 * 49
#define EPS_IN 1e-5f

// ws float offsets
#define WS_G8   0             // [8][4096] split gram partials
#define WS_S8   32768         // [8][64]   split channel sums
#define WS_WM   33280         // [4096]
#define WS_BIAS 37376         // [64]
#define WS_SG   37440         // [4096]

typedef __attribute__((ext_vector_type(8))) short bf16x8_t;   // 8 bf16 = 4 VGPR
typedef __attribute__((ext_vector_type(4))) float f32x4_t;

__device__ __forceinline__ unsigned short f2bf(float f) {
  union { float f; unsigned u; } v; v.f = f;
  unsigned r = v.u + 0x7FFFu + ((v.u >> 16) & 1u);   // round-to-nearest-even
  return (unsigned short)(r >> 16);
}

__device__ __forceinline__ float bf2f(unsigned short h) {
  union { unsigned u; float f; } v; v.u = ((unsigned)h) << 16;
  return v.f;
}

// ---------------- Pass 1: per-channel sums + raw gram G = X X^T (bf16 MFMA) ----
// Tile: one b, 256 contiguous pixels, all 64 channels. Wave load instr = 1 KB
// contiguous; 8 loads in flight per wave (explicit register batch).
__global__ __launch_bounds__(256) void k_gram(const float* __restrict__ x,
                                              float* __restrict__ ws) {
  __shared__ unsigned short xs[64][264];   // +8 pad: rows 528 B (16B-aligned)
  __shared__ float ps[256];
  const int t    = threadIdx.x;
  const int lane = t & 63;
  const int wv   = t >> 6;
  const int bx   = blockIdx.x;
  const int b    = bx / TILES_PER_B;
  const int p0   = (bx - b * TILES_PER_B) * 256;
  const size_t base = (size_t)(b * 64) * HW_PIX + p0 + 4 * (t & 63);

  // ---- staging: 16 float4 per thread, channel c = 4*i + wv, two batches of 8
  #pragma unroll
  for (int h = 0; h < 2; ++h) {
    float4 v[8];
    #pragma unroll
    for (int i = 0; i < 8; ++i) {
      const int c = 4 * (8 * h + i) + wv;
      v[i] = *(const float4*)(x + base + (size_t)c * HW_PIX);
    }
    #pragma unroll
    for (int i = 0; i < 8; ++i) {
      const int c = 4 * (8 * h + i) + wv;
      ushort4 hh;
      hh.x = f2bf(v[i].x); hh.y = f2bf(v[i].y);
      hh.z = f2bf(v[i].z); hh.w = f2bf(v[i].w);
      *(ushort4*)&xs[c][4 * (t & 63)] = hh;
    }
  }
  __syncthreads();

  // ---- MFMA: identical to the R1 (verified-correct) inner loop
  f32x4_t acc[4];
  #pragma unroll
  for (int i = 0; i < 4; ++i) acc[i] = (f32x4_t){0.f, 0.f, 0.f, 0.f};
  #pragma unroll
  for (int ks = 0; ks < 8; ++ks) {
    const int col = ks * 32 + 8 * (lane >> 4);
    bf16x8_t fa = *(const bf16x8_t*)&xs[wv * 16 + (lane & 15)][col];
    #pragma unroll
    for (int cb = 0; cb < 4; ++cb) {
      bf16x8_t fb = *(const bf16x8_t*)&xs[cb * 16 + (lane & 15)][col];
      acc[cb] = __builtin_amdgcn_mfma_f32_16x16x32_bf16(fa, fb, acc[cb], 0, 0, 0);
    }
  }

  // ---- channel sums from staged bf16 (error ~1e-5 in mean, negligible)
  {
    const int c = t >> 2, q = t & 3;
    float s = 0.f;
    #pragma unroll
    for (int j = 0; j < 8; ++j) {
      bf16x8_t u = *(const bf16x8_t*)&xs[c][q * 64 + 8 * j];
      #pragma unroll
      for (int e = 0; e < 8; ++e) s += bf2f((unsigned short)u[e]);
    }
    ps[t] = s;
  }
  __syncthreads();
  if (t < 64) {
    float s4 = ps[4 * t] + ps[4 * t + 1] + ps[4 * t + 2] + ps[4 * t + 3];
    atomicAdd(ws + WS_S8 + (bx & 7) * 64 + t, s4);
  }
  // C/D map (m89-verified): col = lane&15, row = (lane>>4)*4 + reg
  float* G8 = ws + WS_G8 + (size_t)(bx & 7) * 4096;
  const int g = lane >> 4, cl = lane & 15;
  #pragma unroll
  for (int cb = 0; cb < 4; ++cb)
    #pragma unroll
    for (int rg = 0; rg < 4; ++rg)
      atomicAdd(&G8[(wv * 16 + g * 4 + rg) * 64 + cb * 16 + cl], acc[cb][rg]);
}

// ---------------- Pass 2: Newton-Schulz on 64x64, single block -----------------
__device__ __forceinline__ void mm_core(float acc[4][4], const float (*X)[68],
                                        const float (*Y)[68], int iB, int jB) {
  #pragma unroll
  for (int a = 0; a < 4; ++a)
    #pragma unroll
    for (int b = 0; b < 4; ++b) acc[a][b] = 0.f;
  #pragma unroll 4
  for (int kq = 0; kq < 16; ++kq) {
    float4 xr[4], yr[4];
    #pragma unroll
    for (int d = 0; d < 4; ++d) {
      xr[d] = *(const float4*)&X[iB + 16 * d][4 * kq];
      yr[d] = *(const float4*)&Y[jB + 16 * d][4 * kq];
    }
    #pragma unroll
    for (int di = 0; di < 4; ++di)
      #pragma unroll
      for (int dj = 0; dj < 4; ++dj)
        acc[di][dj] += xr[di].x * yr[dj].x + xr[di].y * yr[dj].y +
                       xr[di].z * yr[dj].z + xr[di].w * yr[dj].w;
  }
}

__global__ __launch_bounds__(256) void k_ns(float* __restrict__ ws) {
  float* G8   = ws + WS_G8;
  float* S8   = ws + WS_S8;
  float* wm   = ws + WS_WM;
  float* bias = ws + WS_BIAS;
  float* Sg   = ws + WS_SG;
  __shared__ float bufs[3][64][68];
  __shared__ float mean_s[64];
  __shared__ float r_s;
  const int t = threadIdx.x;
  const float inv_m = 1.0f / (float)M_TOTAL;
  if (t < 64) {
    float s = 0.f;
    #pragma unroll
    for (int k = 0; k < 8; ++k) s += S8[k * 64 + t];
    mean_s[t] = s * inv_m;
  }
  __syncthreads();
  for (int idx = t; idx < 4096; idx += 256) {
    int i = idx >> 6, j = idx & 63;
    float g = 0.f;
    #pragma unroll
    for (int k = 0; k < 8; ++k) g += G8[k * 4096 + idx];
    bufs[1][i][j] = g * inv_m - mean_s[i] * mean_s[j] + ((i == j) ? EPS_IN : 0.f);
  }
  __syncthreads();
  if (t == 0) {
    float tr = 0.f;
    for (int i = 0; i < 64; ++i) tr += bufs[1][i][i];
    r_s = 1.0f / tr;
  }
  __syncthreads();
  const float r = r_s;
  for (int idx = t; idx < 4096; idx += 256) {
    int i = idx >> 6, j = idx & 63;
    Sg[idx] = bufs[1][i][j] * r;
    bufs[0][i][j] = (i == j) ? 1.f : 0.f;
  }
  __syncthreads();
  int pa = 0, pb = 1, pc = 2;
  const int iB = t >> 4, jB = t & 15;
  float acc[4][4];
  for (int itn = 0; itn < 5; ++itn) {
    mm_core(acc, (const float(*)[68])bufs[pa], (const float(*)[68])bufs[pa], iB, jB);
    #pragma unroll
    for (int di = 0; di < 4; ++di)
      #pragma unroll
      for (int dj = 0; dj < 4; ++dj)
        bufs[pb][iB + 16 * di][jB + 16 * dj] = acc[di][dj];
    __syncthreads();
    mm_core(acc, (const float(*)[68])bufs[pb], (const float(*)[68])bufs[pa], iB, jB);
    #pragma unroll
    for (int di = 0; di < 4; ++di)
      #pragma unroll
      for (int dj = 0; dj < 4; ++dj)
        bufs[pc][iB + 16 * di][jB + 16 * dj] = acc[di][dj];
    __syncthreads();
    for (int idx = t; idx < 4096; idx += 256)
      bufs[pb][idx >> 6][idx & 63] = Sg[idx];
    __syncthreads();
    mm_core(acc, (const float(*)[68])bufs[pc], (const float(*)[68])bufs[pb], iB, jB);
    __syncthreads();
    #pragma unroll
    for (int di = 0; di < 4; ++di)
      #pragma unroll
      for (int dj = 0; dj < 4; ++dj) {
        int ii = iB + 16 * di, jj = jB + 16 * dj;
        bufs[pc][ii][jj] = 1.5f * bufs[pa][ii][jj] - 0.5f * acc[di][dj];
      }
    __syncthreads();
    int tmp = pa; pa = pc; pc = tmp;
  }
  const float sr = sqrtf(r);
  for (int idx = t; idx < 4096; idx += 256)
    wm[idx] = bufs[pa][idx >> 6][idx & 63] * sr;
  if (t < 64) {
    float a = 0.f;
    for (int k = 0; k < 64; ++k) a += bufs[pa][t][k] * mean_s[k];
    bias[t] = -a * sr;
  }
}

// ---------------- Pass 3: out = wm*x + bias, LDS-staged, fp32 VALU -------------
__global__ __launch_bounds__(256) void k_apply(const float* __restrict__ x,
                                               const float* __restrict__ ws,
                                               float* __restrict__ out) {
  __shared__ unsigned short xs[64][264];
  const int t  = threadIdx.x;
  const int wv = t >> 6;
  const int bx = blockIdx.x;
  const int b  = bx / TILES_PER_B;
  const int p0 = (bx - b * TILES_PER_B) * 256;
  const size_t cbase = (size_t)(b * 64) * HW_PIX + p0;
  const size_t base  = cbase + 4 * (t & 63);

  #pragma unroll
  for (int h = 0; h < 2; ++h) {
    float4 v[8];
    #pragma unroll
    for (int i = 0; i < 8; ++i) {
      const int c = 4 * (8 * h + i) + wv;
      v[i] = *(const float4*)(x + base + (size_t)c * HW_PIX);
    }
    #pragma unroll
    for (int i = 0; i < 8; ++i) {
      const int c = 4 * (8 * h + i) + wv;
      ushort4 hh;
      hh.x = f2bf(v[i].x); hh.y = f2bf(v[i].y);
      hh.z = f2bf(v[i].z); hh.w = f2bf(v[i].w);
      *(ushort4*)&xs[c][4 * (t & 63)] = hh;
    }
  }
  __syncthreads();

  // xk[64]: this thread's pixel column (broadcast-friendly LDS reads)
  float xk[64];
  #pragma unroll
  for (int k = 0; k < 64; ++k) xk[k] = bf2f(xs[k][t]);

  const float* __restrict__ wm   = ws + WS_WM;    // wave-uniform -> s_load
  const float* __restrict__ bias = ws + WS_BIAS;
  float* ob = out + cbase + t;
  #pragma unroll 2
  for (int c = 0; c < 64; ++c) {
    const float4* wr = (const float4*)(wm + c * 64);
    float a0 = bias[c], a1 = 0.f, a2 = 0.f, a3 = 0.f;
    #pragma unroll
    for (int k4 = 0; k4 < 16; ++k4) {
      float4 w = wr[k4];
      a0 += w.x * xk[4 * k4 + 0];
      a1 += w.y * xk[4 * k4 + 1];
      a2 += w.z * xk[4 * k4 + 2];
      a3 += w.w * xk[4 * k4 + 3];
    }
    ob[(size_t)c * HW_PIX] = (a0 + a1) + (a2 + a3);
  }
}

extern "C" void kernel_launch(void* const* d_in, const int* in_sizes, int n_in,
                              void* d_out, int out_size, void* d_ws, size_t ws_size,
                              hipStream_t stream) {
  const float* x = (const float*)d_in[0];
  float* out = (float*)d_out;
  float* ws  = (float*)d_ws;
  hipMemsetAsync(d_ws, 0, (32768 + 512) * sizeof(float), stream);  // G8 + S8
  k_gram<<<NBLK, 256, 0, stream>>>(x, ws);
  k_ns<<<1, 256, 0, stream>>>(ws);
  k_apply<<<NBLK, 256, 0, stream>>>(x, ws, out);
}

// Round 3
// 457.771 us; speedup vs baseline: 3.2131x; 1.3125x over previous
//
#include <hip/hip_runtime.h>

#define HW_PIX 12544          // 112*112
#define M_TOTAL 802816        // 64*112*112
#define TILES_PER_B 49        // 12544 / 256
#define NTILE 3136            // 64 * 49
#define GRID1 784             // gram: 4 tiles per block
#define EPS_IN 1e-5f

// ws float offsets
#define WS_G8   0             // [8][4096] split gram partials
#define WS_S8   32768         // [8][64]   split channel sums
#define WS_WM   33280         // [4096]
#define WS_BIAS 37376         // [64]
#define WS_SG   37440         // [4096]

typedef __attribute__((ext_vector_type(8))) short bf16x8_t;   // 8 bf16 = 4 VGPR
typedef __attribute__((ext_vector_type(4))) float f32x4_t;

__device__ __forceinline__ unsigned short f2bf(float f) {
  union { float f; unsigned u; } v; v.f = f;
  unsigned r = v.u + 0x7FFFu + ((v.u >> 16) & 1u);   // round-to-nearest-even
  return (unsigned short)(r >> 16);
}

__device__ __forceinline__ float bf2f(unsigned short h) {
  union { unsigned u; float f; } v; v.u = ((unsigned)h) << 16;
  return v.f;
}

// ---------------- Pass 1: per-channel sums + raw gram G = X X^T (bf16 MFMA) ----
// 4 tiles per block; staging identical to R2 (verified); acc/sums held in regs.
__global__ __launch_bounds__(256) void k_gram(const float* __restrict__ x,
                                              float* __restrict__ ws) {
  __shared__ unsigned short xs[64][264];
  __shared__ float ps[256];
  const int t    = threadIdx.x;
  const int lane = t & 63;
  const int wv   = t >> 6;
  const int bx   = blockIdx.x;

  f32x4_t acc[4];
  #pragma unroll
  for (int i = 0; i < 4; ++i) acc[i] = (f32x4_t){0.f, 0.f, 0.f, 0.f};
  float csum = 0.f;

  for (int itc = 0; itc < 4; ++itc) {
    const int ci = bx + itc * GRID1;
    const int b  = ci / TILES_PER_B;
    const int p0 = (ci - b * TILES_PER_B) * 256;
    const size_t base = (size_t)(b * 64) * HW_PIX + p0 + 4 * (t & 63);

    #pragma unroll
    for (int h = 0; h < 2; ++h) {
      float4 v[8];
      #pragma unroll
      for (int i = 0; i < 8; ++i) {
        const int c = 4 * (8 * h + i) + wv;
        v[i] = *(const float4*)(x + base + (size_t)c * HW_PIX);
      }
      #pragma unroll
      for (int i = 0; i < 8; ++i) {
        const int c = 4 * (8 * h + i) + wv;
        ushort4 hh;
        hh.x = f2bf(v[i].x); hh.y = f2bf(v[i].y);
        hh.z = f2bf(v[i].z); hh.w = f2bf(v[i].w);
        *(ushort4*)&xs[c][4 * (t & 63)] = hh;
      }
    }
    __syncthreads();

    #pragma unroll
    for (int ks = 0; ks < 8; ++ks) {
      const int col = ks * 32 + 8 * (lane >> 4);
      bf16x8_t fa = *(const bf16x8_t*)&xs[wv * 16 + (lane & 15)][col];
      #pragma unroll
      for (int cb = 0; cb < 4; ++cb) {
        bf16x8_t fb = *(const bf16x8_t*)&xs[cb * 16 + (lane & 15)][col];
        acc[cb] = __builtin_amdgcn_mfma_f32_16x16x32_bf16(fa, fb, acc[cb], 0, 0, 0);
      }
    }

    {
      const int c = t >> 2, q = t & 3;
      #pragma unroll
      for (int j = 0; j < 8; ++j) {
        bf16x8_t u = *(const bf16x8_t*)&xs[c][q * 64 + 8 * j];
        #pragma unroll
        for (int e = 0; e < 8; ++e) csum += bf2f((unsigned short)u[e]);
      }
    }
    __syncthreads();
  }

  ps[t] = csum;
  __syncthreads();
  if (t < 64) {
    float s4 = ps[4 * t] + ps[4 * t + 1] + ps[4 * t + 2] + ps[4 * t + 3];
    atomicAdd(ws + WS_S8 + (bx & 7) * 64 + t, s4);
  }
  float* G8 = ws + WS_G8 + (size_t)(bx & 7) * 4096;
  const int g = lane >> 4, cl = lane & 15;
  #pragma unroll
  for (int cb = 0; cb < 4; ++cb)
    #pragma unroll
    for (int rg = 0; rg < 4; ++rg)
      atomicAdd(&G8[(wv * 16 + g * 4 + rg) * 64 + cb * 16 + cl], acc[cb][rg]);
}

// ---------------- Pass 2: Newton-Schulz on 64x64, single block -----------------
__device__ __forceinline__ void mm_core(float acc[4][4], const float (*X)[68],
                                        const float (*Y)[68], int iB, int jB) {
  #pragma unroll
  for (int a = 0; a < 4; ++a)
    #pragma unroll
    for (int b = 0; b < 4; ++b) acc[a][b] = 0.f;
  #pragma unroll 4
  for (int kq = 0; kq < 16; ++kq) {
    float4 xr[4], yr[4];
    #pragma unroll
    for (int d = 0; d < 4; ++d) {
      xr[d] = *(const float4*)&X[iB + 16 * d][4 * kq];
      yr[d] = *(const float4*)&Y[jB + 16 * d][4 * kq];
    }
    #pragma unroll
    for (int di = 0; di < 4; ++di)
      #pragma unroll
      for (int dj = 0; dj < 4; ++dj)
        acc[di][dj] += xr[di].x * yr[dj].x + xr[di].y * yr[dj].y +
                       xr[di].z * yr[dj].z + xr[di].w * yr[dj].w;
  }
}

__global__ __launch_bounds__(256) void k_ns(float* __restrict__ ws) {
  float* G8   = ws + WS_G8;
  float* S8   = ws + WS_S8;
  float* wm   = ws + WS_WM;
  float* bias = ws + WS_BIAS;
  float* Sg   = ws + WS_SG;
  __shared__ float bufs[3][64][68];
  __shared__ float mean_s[64];
  __shared__ float r_s;
  const int t = threadIdx.x;
  const float inv_m = 1.0f / (float)M_TOTAL;
  if (t < 64) {
    float s = 0.f;
    #pragma unroll
    for (int k = 0; k < 8; ++k) s += S8[k * 64 + t];
    mean_s[t] = s * inv_m;
  }
  __syncthreads();
  for (int idx = t; idx < 4096; idx += 256) {
    int i = idx >> 6, j = idx & 63;
    float g = 0.f;
    #pragma unroll
    for (int k = 0; k < 8; ++k) g += G8[k * 4096 + idx];
    bufs[1][i][j] = g * inv_m - mean_s[i] * mean_s[j] + ((i == j) ? EPS_IN : 0.f);
  }
  __syncthreads();
  if (t == 0) {
    float tr = 0.f;
    for (int i = 0; i < 64; ++i) tr += bufs[1][i][i];
    r_s = 1.0f / tr;
  }
  __syncthreads();
  const float r = r_s;
  for (int idx = t; idx < 4096; idx += 256) {
    int i = idx >> 6, j = idx & 63;
    Sg[idx] = bufs[1][i][j] * r;
    bufs[0][i][j] = (i == j) ? 1.f : 0.f;
  }
  __syncthreads();
  int pa = 0, pb = 1, pc = 2;
  const int iB = t >> 4, jB = t & 15;
  float acc[4][4];
  for (int itn = 0; itn < 5; ++itn) {
    mm_core(acc, (const float(*)[68])bufs[pa], (const float(*)[68])bufs[pa], iB, jB);
    #pragma unroll
    for (int di = 0; di < 4; ++di)
      #pragma unroll
      for (int dj = 0; dj < 4; ++dj)
        bufs[pb][iB + 16 * di][jB + 16 * dj] = acc[di][dj];
    __syncthreads();
    mm_core(acc, (const float(*)[68])bufs[pb], (const float(*)[68])bufs[pa], iB, jB);
    #pragma unroll
    for (int di = 0; di < 4; ++di)
      #pragma unroll
      for (int dj = 0; dj < 4; ++dj)
        bufs[pc][iB + 16 * di][jB + 16 * dj] = acc[di][dj];
    __syncthreads();
    for (int idx = t; idx < 4096; idx += 256)
      bufs[pb][idx >> 6][idx & 63] = Sg[idx];
    __syncthreads();
    mm_core(acc, (const float(*)[68])bufs[pc], (const float(*)[68])bufs[pb], iB, jB);
    __syncthreads();
    #pragma unroll
    for (int di = 0; di < 4; ++di)
      #pragma unroll
      for (int dj = 0; dj < 4; ++dj) {
        int ii = iB + 16 * di, jj = jB + 16 * dj;
        bufs[pc][ii][jj] = 1.5f * bufs[pa][ii][jj] - 0.5f * acc[di][dj];
      }
    __syncthreads();
    int tmp = pa; pa = pc; pc = tmp;
  }
  const float sr = sqrtf(r);
  for (int idx = t; idx < 4096; idx += 256)
    wm[idx] = bufs[pa][idx >> 6][idx & 63] * sr;
  if (t < 64) {
    float a = 0.f;
    for (int k = 0; k < 64; ++k) a += bufs[pa][t][k] * mean_s[k];
    bias[t] = -a * sr;
  }
}

// ---------------- Pass 3: out = wm*x + bias via MFMA, transposed LDS -----------
// K-permutation: position P <-> channel c = 4*(P&15) + (P>>4); A and B both use
// it, so the contraction is exact. wm split hi+lo bf16 -> ~fp32 wm precision.
__global__ __launch_bounds__(256) void k_apply(const float* __restrict__ x,
                                               const float* __restrict__ ws,
                                               float* __restrict__ out) {
  __shared__ unsigned short Y[256][68];   // [pixel][P], row 136 B (8B-aligned)
  const int t    = threadIdx.x;
  const int lane = t & 63;
  const int wv   = t >> 6;
  const int g    = lane >> 4;
  const int m    = lane & 15;
  const int bx   = blockIdx.x;
  const int b    = bx / TILES_PER_B;
  const int p0   = (bx - b * TILES_PER_B) * 256;
  const float* __restrict__ wm   = ws + WS_WM;
  const float* __restrict__ bias = ws + WS_BIAS;

  // ---- A-frags (wm rows, hi/lo split) + bias, in registers
  const int arow = wv * 16 + m;
  bf16x8_t aHi[2], aLo[2];
  #pragma unroll
  for (int ks = 0; ks < 2; ++ks) {
    #pragma unroll
    for (int e = 0; e < 8; ++e) {
      const int P = ks * 32 + g * 8 + e;
      const int c = 4 * (P & 15) + (P >> 4);
      float f = wm[arow * 64 + c];
      unsigned short hi = f2bf(f);
      unsigned short lo = f2bf(f - bf2f(hi));
      aHi[ks][e] = (short)hi;
      aLo[ks][e] = (short)lo;
    }
  }
  float bv[4];
  #pragma unroll
  for (int rr = 0; rr < 4; ++rr) bv[rr] = bias[wv * 16 + g * 4 + rr];

  // ---- stage: thread t owns pixel p0+t, loads 64 channels as scalar dwords
  const size_t gbase = (size_t)(b * 64) * HW_PIX + p0 + t;
  #pragma unroll
  for (int r = 0; r < 4; ++r) {
    float f[16];
    #pragma unroll
    for (int j = 0; j < 16; ++j)
      f[j] = x[gbase + (size_t)(4 * j + r) * HW_PIX];
    #pragma unroll
    for (int q = 0; q < 4; ++q) {
      ushort4 u;
      u.x = f2bf(f[4 * q + 0]); u.y = f2bf(f[4 * q + 1]);
      u.z = f2bf(f[4 * q + 2]); u.w = f2bf(f[4 * q + 3]);
      *(ushort4*)&Y[t][16 * r + 4 * q] = u;   // P = 16r + 4q + e
    }
  }
  __syncthreads();

  // ---- MFMA: wave wv owns out rows [wv*16, wv*16+16), 16 pixel-tiles
  const size_t obase = (size_t)(b * 64) * HW_PIX + p0;
  #pragma unroll 2
  for (int tile = 0; tile < 16; ++tile) {
    const int pcol = tile * 16 + m;
    bf16x8_t bf[2];
    #pragma unroll
    for (int ks = 0; ks < 2; ++ks) {
      union { ushort4 u2[2]; bf16x8_t v; } cu;
      cu.u2[0] = *(const ushort4*)&Y[pcol][ks * 32 + g * 8];
      cu.u2[1] = *(const ushort4*)&Y[pcol][ks * 32 + g * 8 + 4];
      bf[ks] = cu.v;
    }
    f32x4_t acc = (f32x4_t){bv[0], bv[1], bv[2], bv[3]};
    acc = __builtin_amdgcn_mfma_f32_16x16x32_bf16(aHi[0], bf[0], acc, 0, 0, 0);
    acc = __builtin_amdgcn_mfma_f32_16x16x32_bf16(aHi[1], bf[1], acc, 0, 0, 0);
    acc = __builtin_amdgcn_mfma_f32_16x16x32_bf16(aLo[0], bf[0], acc, 0, 0, 0);
    acc = __builtin_amdgcn_mfma_f32_16x16x32_bf16(aLo[1], bf[1], acc, 0, 0, 0);
    // D map: col = lane&15, row = (lane>>4)*4 + reg
    #pragma unroll
    for (int rr = 0; rr < 4; ++rr)
      out[obase + (size_t)(wv * 16 + g * 4 + rr) * HW_PIX + tile * 16 + m] = acc[rr];
  }
}

extern "C" void kernel_launch(void* const* d_in, const int* in_sizes, int n_in,
                              void* d_out, int out_size, void* d_ws, size_t ws_size,
                              hipStream_t stream) {
  const float* x = (const float*)d_in[0];
  float* out = (float*)d_out;
  float* ws  = (float*)d_ws;
  hipMemsetAsync(d_ws, 0, (32768 + 512) * sizeof(float), stream);  // G8 + S8
  k_gram<<<GRID1, 256, 0, stream>>>(x, ws);
  k_ns<<<1, 256, 0, stream>>>(ws);
  k_apply<<<NTILE, 256, 0, stream>>>(x, ws, out);
}